// Round 10
// baseline (1034.759 us; speedup 1.0000x reference)
//
#include <hip/hip_runtime.h>
#include <hip/hip_bf16.h>

// AdditiveAttention, restructured + m97-style MFMA GEMM (global_load_lds).
//
// Algebraic reassociation (removes 34.4 GF N-GEMM + kproj + mb L2 pass):
//   Gt   = W_q @ W_k^T                          [1024,1024]  (bf16, once)
//   P[b] = keys[b] @ Gt^T                       [128(pad50),1024] (f32)
//   N[b,v,i] = (1/32) sum_k W_o[k,v] P[b,k,i]   [512,1024]   (bf16)
//   logits[b,v,q] = sum_i N[b,v,i]*qb[b,q,i]    -> d_out attn region (f32)
//   attn = softmax(mask(logits))                f32 -> d_out; bf16 -> attnb
//   T    = attnb @ values  (via vT)             [512,1024] (bf16)
//   out  = T @ W_v (via wvT)                    [512,1024] (f32)
//
// GEMM: 128x128x64 tile, 4 waves, LINEAR LDS [128][64] staged via
// global_load_lds_dwordx4 (m97 structure) + XCD-chunked swizzle (T1/m204)
// with y-fastest intra-chunk order so each batch's panels stay in one
// XCD's 4MB L2 (per-XCD working set <= 2.5 MB for all five GEMM launches).

#define NB   32
#define LQ   2048
#define LK   50
#define DIN  1024
#define DHID 1024
#define DVAL 512

typedef short bf16x8 __attribute__((ext_vector_type(8)));
typedef float f32x4  __attribute__((ext_vector_type(4)));
typedef unsigned short u16x8 __attribute__((ext_vector_type(8)));
typedef unsigned short u16x4 __attribute__((ext_vector_type(4)));

static __device__ __forceinline__ unsigned short f2b(float f) {
  __hip_bfloat16 h = __float2bfloat16(f);
  unsigned short u;
  __builtin_memcpy(&u, &h, 2);
  return u;
}

// async global->LDS, 16B per lane (global_load_lds_dwordx4)
static __device__ __forceinline__ void gload_lds16(const void* g, void* l) {
  __builtin_amdgcn_global_load_lds(
      (const __attribute__((address_space(1))) void*)g,
      (__attribute__((address_space(3))) void*)l, 16, 0, 0);
}

// ---------------- f32 -> bf16 elementwise (n multiple of 2048) -------------
__global__ __launch_bounds__(256) void cvt_bf16_kernel(
    const float* __restrict__ in, unsigned short* __restrict__ outp, long n) {
  const long i = ((long)blockIdx.x * 256 + threadIdx.x) * 8;
  if (i >= n) return;
  const float4 a = *reinterpret_cast<const float4*>(in + i);
  const float4 b = *reinterpret_cast<const float4*>(in + i + 4);
  u16x8 p;
  p[0] = f2b(a.x); p[1] = f2b(a.y); p[2] = f2b(a.z); p[3] = f2b(a.w);
  p[4] = f2b(b.x); p[5] = f2b(b.y); p[6] = f2b(b.z); p[7] = f2b(b.w);
  *reinterpret_cast<u16x8*>(outp + i) = p;
}

// ---------------- transpose + convert: in f32 [R,C] -> out bf16 [C,R] ------
__global__ __launch_bounds__(256) void transpose_bf16_kernel(
    const float* __restrict__ in, unsigned short* __restrict__ outp,
    int R, int C, long sIn, long sOut) {
  __shared__ float t[64][65];
  in   += (long)blockIdx.z * sIn;
  outp += (long)blockIdx.z * sOut;
  const int r0 = blockIdx.y * 64, c0 = blockIdx.x * 64;
  const int tid = threadIdx.x;
  const int lr = tid >> 4;          // 0..15
  const int lc = (tid & 15) * 4;    // 0..60
#pragma unroll
  for (int u = 0; u < 4; ++u) {
    const float4 v = *reinterpret_cast<const float4*>(
        in + (long)(r0 + lr + u * 16) * C + c0 + lc);
    t[lc + 0][lr + u * 16] = v.x; t[lc + 1][lr + u * 16] = v.y;
    t[lc + 2][lr + u * 16] = v.z; t[lc + 3][lr + u * 16] = v.w;
  }
  __syncthreads();
  const int orow = tid >> 2;        // 0..63 (output row, = input col)
  const int oseg = (tid & 3) * 16;  // 16 elements
  u16x8 p0, p1;
#pragma unroll
  for (int u = 0; u < 8; ++u) p0[u] = f2b(t[orow][oseg + u]);
#pragma unroll
  for (int u = 0; u < 8; ++u) p1[u] = f2b(t[orow][oseg + 8 + u]);
  unsigned short* o = outp + (long)(c0 + orow) * R + r0 + oseg;
  *reinterpret_cast<u16x8*>(o)     = p0;
  *reinterpret_cast<u16x8*>(o + 8) = p1;
}

// ---------------- keys f32 [B,50,1024] -> padded bf16 [B,128,1024] ---------
__global__ __launch_bounds__(256) void kb_kernel(
    const float* __restrict__ keys, unsigned short* __restrict__ kb) {
  const int row = blockIdx.x;       // 0..B*128-1
  const int b = row >> 7, r = row & 127;
  const int t = threadIdx.x;
  u16x4 o;
  if (r < LK) {
    const float4 v = *reinterpret_cast<const float4*>(
        keys + ((long)b * LK + r) * DIN + t * 4);
    o[0] = f2b(v.x); o[1] = f2b(v.y); o[2] = f2b(v.z); o[3] = f2b(v.w);
  } else {
    o[0] = 0; o[1] = 0; o[2] = 0; o[3] = 0;
  }
  *reinterpret_cast<u16x4*>(kb + (long)row * DIN + t * 4) = o;
}

// ---------- Nb[b,v,i] = bf16((1/32) sum_{k<50} W_o[k,v] * P[b,k,i]) --------
#define VB 8
__global__ __launch_bounds__(256) void nb_kernel(
    const float* __restrict__ P, const float* __restrict__ W_o,
    unsigned short* __restrict__ Nb) {
  const int blk = blockIdx.x;                  // NB * (DVAL/VB)
  const int b  = blk / (DVAL / VB);
  const int v0 = (blk % (DVAL / VB)) * VB;
  const int t  = threadIdx.x;
  const float* Pb = P + (long)b * 128 * DHID + t * 4;
  f32x4 acc[VB];
#pragma unroll
  for (int u = 0; u < VB; ++u) acc[u] = (f32x4)(0.0f);
  for (int k = 0; k < LK; ++k) {
    const f32x4 pv = *reinterpret_cast<const f32x4*>(Pb + (long)k * DHID);
#pragma unroll
    for (int u = 0; u < VB; ++u) {
      const float wo = W_o[k * DVAL + v0 + u];
      acc[u] += pv * wo;
    }
  }
#pragma unroll
  for (int u = 0; u < VB; ++u) {
    u16x4 r;
    r[0] = f2b(acc[u][0] * 0.03125f); r[1] = f2b(acc[u][1] * 0.03125f);
    r[2] = f2b(acc[u][2] * 0.03125f); r[3] = f2b(acc[u][3] * 0.03125f);
    *reinterpret_cast<u16x4*>(
        Nb + ((long)b * DVAL + v0 + u) * DHID + t * 4) = r;
  }
}

// ---------------- bf16 MFMA GEMM, both operands [rows, K] row-major --------
// C[m,n] = sum_k A[m*lda+k] * B[n*ldb+k]
// m97 structure: linear LDS [128][64], global_load_lds width=16.
// REQUIRES: total workgroup count divisible by 8 (bijective XCD swizzle).
#define BM 128
#define BN 128
#define BK 64

template <typename OT>
__global__ __launch_bounds__(256, 3) void gemm_bt_kernel(
    const unsigned short* __restrict__ Ag, const unsigned short* __restrict__ Bg,
    OT* __restrict__ Cg, int K, int lda, int ldb, int ldc,
    long sA, long sB, long sC) {
  __shared__ __attribute__((aligned(16))) unsigned short As[BM * BK];
  __shared__ __attribute__((aligned(16))) unsigned short Bs[BN * BK];

  const int tid = threadIdx.x;

  // XCD-chunked bijective swizzle (T1, m157/m204): dispatch round-robins
  // linear wg id across 8 XCDs, so (lin & 7) == XCD. Map each XCD to a
  // contiguous chunk of work; y-fastest within chunk so one B-panel
  // (x fixed, 256-512 KB) is reused across all y while the batch's A
  // (1-2 MB) stays resident in that XCD's 4 MB L2.
  const int gx  = gridDim.x, gy = gridDim.y;
  const int gxy = gx * gy;
  const int nwg = gxy * gridDim.z;
  const int lin = (blockIdx.z * gy + blockIdx.y) * gx + blockIdx.x;
  const int swz = (lin & 7) * (nwg >> 3) + (lin >> 3);
  const int bz  = swz / gxy;
  const int rem = swz - bz * gxy;
  const int bx  = rem / gy;
  const int by  = rem - bx * gy;

  Ag += (long)bz * sA;
  Bg += (long)bz * sB;
  Cg += (long)bz * sC;
  const int m0 = by * BM;
  const int n0 = bx * BN;

  const int w    = tid >> 6;
  const int lane = tid & 63;
  const int l15  = lane & 15;
  const int quad = lane >> 4;
  const int wm   = (w >> 1) * 64;
  const int wn   = (w & 1) * 64;

  // staging: round r (0..3) covers rows r*32 + w*8 + (lane>>3); lane covers
  // 8 bf16 (16B) at col (lane&7)*8. LDS offset = uniform base + lane*16B.
  const int srow = w * 8 + (lane >> 3);
  const int scol = (lane & 7) * 8;
  const unsigned short* aptr = Ag + (long)(m0 + srow) * lda + scol;
  const unsigned short* bptr = Bg + (long)(n0 + srow) * ldb + scol;
  unsigned short* adst = &As[srow * BK + scol];
  unsigned short* bdst = &Bs[srow * BK + scol];

  f32x4 acc[4][4];
#pragma unroll
  for (int i = 0; i < 4; ++i)
#pragma unroll
    for (int j = 0; j < 4; ++j) acc[i][j] = (f32x4)(0.0f);

  for (int k0 = 0; k0 < K; k0 += BK) {
#pragma unroll
    for (int r = 0; r < 4; ++r)
      gload_lds16(aptr + (long)(r * 32) * lda + k0, adst + r * 32 * BK);
#pragma unroll
    for (int r = 0; r < 4; ++r)
      gload_lds16(bptr + (long)(r * 32) * ldb + k0, bdst + r * 32 * BK);
    __syncthreads();   // compiler emits vmcnt(0) drain before barrier

#pragma unroll
    for (int ks = 0; ks < BK; ks += 32) {
      bf16x8 af[4], bfv[4];
#pragma unroll
      for (int i = 0; i < 4; ++i)
        af[i] = *reinterpret_cast<const bf16x8*>(
            &As[(wm + i * 16 + l15) * BK + ks + quad * 8]);
#pragma unroll
      for (int j = 0; j < 4; ++j)
        bfv[j] = *reinterpret_cast<const bf16x8*>(
            &Bs[(wn + j * 16 + l15) * BK + ks + quad * 8]);
#pragma unroll
      for (int i = 0; i < 4; ++i)
#pragma unroll
        for (int j = 0; j < 4; ++j)
          acc[i][j] = __builtin_amdgcn_mfma_f32_16x16x32_bf16(
              af[i], bfv[j], acc[i][j], 0, 0, 0);
    }
    __syncthreads();
  }

  // epilogue: D row = wm+i*16+quad*4+r, col = wn+j*16+l15
#pragma unroll
  for (int i = 0; i < 4; ++i) {
#pragma unroll
    for (int j = 0; j < 4; ++j) {
#pragma unroll
      for (int r = 0; r < 4; ++r) {
        const int row = m0 + wm + i * 16 + quad * 4 + r;
        const int col = n0 + wn + j * 16 + l15;
        const float val = acc[i][j][r];
        if constexpr (sizeof(OT) == 2) {
          reinterpret_cast<__hip_bfloat16*>(Cg)[(long)row * ldc + col] =
              __float2bfloat16(val);
        } else {
          reinterpret_cast<float*>(Cg)[(long)row * ldc + col] = val;
        }
      }
    }
  }
}

// ---------------- masked softmax over q; f32 in-place + bf16 copy ----------
__global__ __launch_bounds__(256) void softmax_kernel(
    float* __restrict__ attn, unsigned short* __restrict__ attnb,
    const int* __restrict__ vlens) {
  __shared__ float smax[4], ssum[4];
  const long base = (long)blockIdx.x * LQ;
  const int vl = vlens[blockIdx.x >> 9];
  const int t = threadIdx.x;
  float x[8];
  float mx = -3.0e38f;
#pragma unroll
  for (int u = 0; u < 8; ++u) {
    const int q = u * 256 + t;
    float v = attn[base + q];
    if (q >= vl) v = -1000000.0f;
    x[u] = v;
    mx = fmaxf(mx, v);
  }
#pragma unroll
  for (int off = 32; off > 0; off >>= 1) mx = fmaxf(mx, __shfl_down(mx, off));
  if ((t & 63) == 0) smax[t >> 6] = mx;
  __syncthreads();
  mx = fmaxf(fmaxf(smax[0], smax[1]), fmaxf(smax[2], smax[3]));
  float s = 0.f;
#pragma unroll
  for (int u = 0; u < 8; ++u) { x[u] = __expf(x[u] - mx); s += x[u]; }
#pragma unroll
  for (int off = 32; off > 0; off >>= 1) s += __shfl_down(s, off);
  if ((t & 63) == 0) ssum[t >> 6] = s;
  __syncthreads();
  s = ssum[0] + ssum[1] + ssum[2] + ssum[3];
  const float inv = 1.0f / s;
#pragma unroll
  for (int u = 0; u < 8; ++u) {
    const float v = x[u] * inv;
    attn[base + u * 256 + t] = v;
    attnb[base + u * 256 + t] = f2b(v);
  }
}

extern "C" void kernel_launch(void* const* d_in, const int* in_sizes, int n_in,
                              void* d_out, int out_size, void* d_ws, size_t ws_size,
                              hipStream_t stream) {
  const float* queries = (const float*)d_in[0];
  const float* keys    = (const float*)d_in[1];
  const float* values  = (const float*)d_in[2];
  const int*   vlens   = (const int*)d_in[3];
  const float* W_q     = (const float*)d_in[4];
  const float* W_k     = (const float*)d_in[5];
  const float* W_v     = (const float*)d_in[6];
  const float* W_o     = (const float*)d_in[7];

  float* out  = (float*)d_out;                       // [32][512][1024]
  float* attn = out + (size_t)NB * DVAL * DHID;      // [32][512][2048] f32

  // workspace layout (aliased by liveness; peak ~239 MB)
  char* ws = (char*)d_ws;
  unsigned short* qb    = (unsigned short*)(ws + 0);          // 134.2 MB; later vT
  unsigned short* vT    = qb;                                  // alias (qb dead after logits)
  // region R [134.2M, 201.3M): kb/Pb/Gt/wkb early, attnb late (all dead by softmax)
  unsigned short* kb    = (unsigned short*)(ws + 134217728UL); // 8.4 MB  [32][128][1024] bf16
  float*          Pb    = (float*)(ws + 142606336UL);          // 16.8 MB [32][128][1024] f32
  unsigned short* Gt    = (unsigned short*)(ws + 159383552UL); // 2.1 MB  [1024][1024] bf16
  unsigned short* wkb   = (unsigned short*)(ws + 161480704UL); // 2.1 MB
  unsigned short* attnb = (unsigned short*)(ws + 134217728UL); // 67 MB alias of R
  unsigned short* Nb    = (unsigned short*)(ws + 201326592UL); // 33.5 MB; later Tb
  unsigned short* Tb    = Nb;                                  // alias (Nb dead after logits)
  unsigned short* wqb   = (unsigned short*)(ws + 234881024UL); // 2.1 MB
  unsigned short* wvT   = (unsigned short*)(ws + 236978176UL); // 2.1 MB

  // --- pre-pass conversions ---
  cvt_bf16_kernel<<<dim3(32768), 256, 0, stream>>>(queries, qb, (long)NB * LQ * DIN);
  cvt_bf16_kernel<<<dim3(512),   256, 0, stream>>>(W_q, wqb, (long)DIN * DHID);
  cvt_bf16_kernel<<<dim3(512),   256, 0, stream>>>(W_k, wkb, (long)DIN * DHID);
  transpose_bf16_kernel<<<dim3(16, 16, 1), 256, 0, stream>>>(W_v, wvT, DIN, DHID, 0, 0);
  kb_kernel<<<dim3(NB * 128), 256, 0, stream>>>(keys, kb);

  // Gt = W_q @ W_k^T : M=1024,N=1024,K=1024 (once, shared over batches)
  gemm_bt_kernel<__hip_bfloat16><<<dim3(8, 8, 1), 256, 0, stream>>>(
      wqb, wkb, (__hip_bfloat16*)Gt, 1024, 1024, 1024, 1024, 0, 0, 0);

  // P[b] = kb[b] @ Gt^T : M=128,N=1024,K=1024 -> f32
  gemm_bt_kernel<float><<<dim3(8, 1, NB), 256, 0, stream>>>(
      kb, Gt, Pb, 1024, 1024, 1024, 1024,
      (long)128 * 1024, 0, (long)128 * 1024);

  // Nb[b,v,i] = bf16((1/32) sum_k W_o[k,v] P[b,k,i])
  nb_kernel<<<dim3(NB * (DVAL / VB)), 256, 0, stream>>>(Pb, W_o, Nb);

  // logits[b] = Nb[b] @ qb[b]^T : M=512,N=2048,K=1024 -> d_out attn region
  gemm_bt_kernel<float><<<dim3(16, 4, NB), 256, 0, stream>>>(
      Nb, qb, attn, 1024, 1024, 1024, 2048,
      (long)512 * 1024, (long)2048 * 1024, (long)512 * 2048);

  // vT[b] = bf16(values[b]^T) : [2048,1024] -> [1024,2048]  (qb now dead)
  transpose_bf16_kernel<<<dim3(16, 32, NB), 256, 0, stream>>>(
      values, vT, LQ, DIN, (long)LQ * DIN, (long)DIN * LQ);

  softmax_kernel<<<dim3(NB * DVAL), 256, 0, stream>>>(attn, attnb, vlens);

  // T[b] = attnb[b] @ values[b] : M=512,N=1024,K=2048
  gemm_bt_kernel<__hip_bfloat16><<<dim3(8, 4, NB), 256, 0, stream>>>(
      attnb, vT, (__hip_bfloat16*)Tb, 2048, 2048, 2048, 1024,
      (long)512 * 2048, (long)1024 * 2048, (long)512 * 1024);

  // out[b] = T[b] @ W_v : M=512,N=1024,K=1024
  gemm_bt_kernel<float><<<dim3(8, 4, NB), 256, 0, stream>>>(
      Tb, wvT, out, 1024, 1024, 1024, 1024,
      (long)512 * 1024, 0, (long)512 * 1024);
}

// Round 11
// 1001.208 us; speedup vs baseline: 1.0335x; 1.0335x over previous
//
#include <hip/hip_runtime.h>
#include <hip/hip_bf16.h>

// AdditiveAttention, restructured + deep-pipelined MFMA GEMM.
//
// Algebra:
//   Gt   = W_q @ W_k^T                          [1024,1024]  (bf16, once)
//   P[b] = keys[b] @ Gt^T                       [128(pad50),1024] (f32)
//   N[b,v,i] = (1/32) sum_k W_o[k,v] P[b,k,i]   [512,1024]   (bf16)
//   logits[b,v,q] = sum_i N[b,v,i]*qb[b,q,i]    -> d_out attn region (f32)
//   attn = softmax(mask(logits))                f32 -> d_out; bf16 -> attnb
//   T    = attnb @ values  (via vT)             [512,1024] (bf16)
//   out  = T @ W_v (via wvT)                    [512,1024] (f32)
//
// GEMM: 128x128x64 tile, 4 waves, double-buffered LDS, global_load_lds w=16,
// counted s_waitcnt vmcnt(8) (never 0 in steady state) + raw s_barrier
// (T3/T4, m218), LDS XOR-swizzle with pre-swizzled global source (T2,
// rule #21: linear dest + inverse-swz source + swz read), s_setprio around
// MFMA clusters (T5). XCD-chunked blockIdx swizzle kept (flat at R10, not
// harmful). Pipeline: stage(t+2) issued right after all waves finish
// reading buf[t&1]; vmcnt(8) guarantees tile t+1 landed before its compute.

#define NB   32
#define LQ   2048
#define LK   50
#define DIN  1024
#define DHID 1024
#define DVAL 512

typedef short bf16x8 __attribute__((ext_vector_type(8)));
typedef float f32x4  __attribute__((ext_vector_type(4)));
typedef unsigned short u16x8 __attribute__((ext_vector_type(8)));
typedef unsigned short u16x4 __attribute__((ext_vector_type(4)));

static __device__ __forceinline__ unsigned short f2b(float f) {
  __hip_bfloat16 h = __float2bfloat16(f);
  unsigned short u;
  __builtin_memcpy(&u, &h, 2);
  return u;
}

// async global->LDS, 16B per lane (global_load_lds_dwordx4)
static __device__ __forceinline__ void gload_lds16(const void* g, void* l) {
  __builtin_amdgcn_global_load_lds(
      (const __attribute__((address_space(1))) void*)g,
      (__attribute__((address_space(3))) void*)l, 16, 0, 0);
}

// ---------------- f32 -> bf16 elementwise (n multiple of 2048) -------------
__global__ __launch_bounds__(256) void cvt_bf16_kernel(
    const float* __restrict__ in, unsigned short* __restrict__ outp, long n) {
  const long i = ((long)blockIdx.x * 256 + threadIdx.x) * 8;
  if (i >= n) return;
  const float4 a = *reinterpret_cast<const float4*>(in + i);
  const float4 b = *reinterpret_cast<const float4*>(in + i + 4);
  u16x8 p;
  p[0] = f2b(a.x); p[1] = f2b(a.y); p[2] = f2b(a.z); p[3] = f2b(a.w);
  p[4] = f2b(b.x); p[5] = f2b(b.y); p[6] = f2b(b.z); p[7] = f2b(b.w);
  *reinterpret_cast<u16x8*>(outp + i) = p;
}

// ---------------- transpose + convert: in f32 [R,C] -> out bf16 [C,R] ------
__global__ __launch_bounds__(256) void transpose_bf16_kernel(
    const float* __restrict__ in, unsigned short* __restrict__ outp,
    int R, int C, long sIn, long sOut) {
  __shared__ float t[64][65];
  in   += (long)blockIdx.z * sIn;
  outp += (long)blockIdx.z * sOut;
  const int r0 = blockIdx.y * 64, c0 = blockIdx.x * 64;
  const int tid = threadIdx.x;
  const int lr = tid >> 4;          // 0..15
  const int lc = (tid & 15) * 4;    // 0..60
#pragma unroll
  for (int u = 0; u < 4; ++u) {
    const float4 v = *reinterpret_cast<const float4*>(
        in + (long)(r0 + lr + u * 16) * C + c0 + lc);
    t[lc + 0][lr + u * 16] = v.x; t[lc + 1][lr + u * 16] = v.y;
    t[lc + 2][lr + u * 16] = v.z; t[lc + 3][lr + u * 16] = v.w;
  }
  __syncthreads();
  const int orow = tid >> 2;        // 0..63 (output row, = input col)
  const int oseg = (tid & 3) * 16;  // 16 elements
  u16x8 p0, p1;
#pragma unroll
  for (int u = 0; u < 8; ++u) p0[u] = f2b(t[orow][oseg + u]);
#pragma unroll
  for (int u = 0; u < 8; ++u) p1[u] = f2b(t[orow][oseg + 8 + u]);
  unsigned short* o = outp + (long)(c0 + orow) * R + r0 + oseg;
  *reinterpret_cast<u16x8*>(o)     = p0;
  *reinterpret_cast<u16x8*>(o + 8) = p1;
}

// ---------------- keys f32 [B,50,1024] -> padded bf16 [B,128,1024] ---------
__global__ __launch_bounds__(256) void kb_kernel(
    const float* __restrict__ keys, unsigned short* __restrict__ kb) {
  const int row = blockIdx.x;       // 0..B*128-1
  const int b = row >> 7, r = row & 127;
  const int t = threadIdx.x;
  u16x4 o;
  if (r < LK) {
    const float4 v = *reinterpret_cast<const float4*>(
        keys + ((long)b * LK + r) * DIN + t * 4);
    o[0] = f2b(v.x); o[1] = f2b(v.y); o[2] = f2b(v.z); o[3] = f2b(v.w);
  } else {
    o[0] = 0; o[1] = 0; o[2] = 0; o[3] = 0;
  }
  *reinterpret_cast<u16x4*>(kb + (long)row * DIN + t * 4) = o;
}

// ---------- Nb[b,v,i] = bf16((1/32) sum_{k<50} W_o[k,v] * P[b,k,i]) --------
#define VB 8
__global__ __launch_bounds__(256) void nb_kernel(
    const float* __restrict__ P, const float* __restrict__ W_o,
    unsigned short* __restrict__ Nb) {
  const int blk = blockIdx.x;                  // NB * (DVAL/VB)
  const int b  = blk / (DVAL / VB);
  const int v0 = (blk % (DVAL / VB)) * VB;
  const int t  = threadIdx.x;
  const float* Pb = P + (long)b * 128 * DHID + t * 4;
  f32x4 acc[VB];
#pragma unroll
  for (int u = 0; u < VB; ++u) acc[u] = (f32x4)(0.0f);
  for (int k = 0; k < LK; ++k) {
    const f32x4 pv = *reinterpret_cast<const f32x4*>(Pb + (long)k * DHID);
#pragma unroll
    for (int u = 0; u < VB; ++u) {
      const float wo = W_o[k * DVAL + v0 + u];
      acc[u] += pv * wo;
    }
  }
#pragma unroll
  for (int u = 0; u < VB; ++u) {
    u16x4 r;
    r[0] = f2b(acc[u][0] * 0.03125f); r[1] = f2b(acc[u][1] * 0.03125f);
    r[2] = f2b(acc[u][2] * 0.03125f); r[3] = f2b(acc[u][3] * 0.03125f);
    *reinterpret_cast<u16x4*>(
        Nb + ((long)b * DVAL + v0 + u) * DHID + t * 4) = r;
  }
}

// ---------------- bf16 MFMA GEMM, both operands [rows, K] row-major --------
// C[m,n] = sum_k A[m*lda+k] * B[n*ldb+k]
// Deep-pipelined: dbuf LDS, counted vmcnt(8), raw barriers, T2 XOR swizzle.
// REQUIRES: total workgroup count divisible by 8; K multiple of 64, K>=128.
#define BM 128
#define BN 128
#define BK 64

template <typename OT>
__global__ __launch_bounds__(256, 2) void gemm_bt_kernel(
    const unsigned short* __restrict__ Ag, const unsigned short* __restrict__ Bg,
    OT* __restrict__ Cg, int K, int lda, int ldb, int ldc,
    long sA, long sB, long sC) {
  __shared__ __attribute__((aligned(16))) unsigned short As[2][BM * BK];
  __shared__ __attribute__((aligned(16))) unsigned short Bs[2][BN * BK];

  const int tid = threadIdx.x;

  // XCD-chunked bijective swizzle (T1, m204): (lin&7)==XCD; y-fastest chunks.
  const int gx  = gridDim.x, gy = gridDim.y;
  const int gxy = gx * gy;
  const int nwg = gxy * gridDim.z;
  const int lin = (blockIdx.z * gy + blockIdx.y) * gx + blockIdx.x;
  const int swz = (lin & 7) * (nwg >> 3) + (lin >> 3);
  const int bz  = swz / gxy;
  const int rem = swz - bz * gxy;
  const int bx  = rem / gy;
  const int by  = rem - bx * gy;

  Ag += (long)bz * sA;
  Bg += (long)bz * sB;
  Cg += (long)bz * sC;
  const int m0 = by * BM;
  const int n0 = bx * BN;

  const int w    = tid >> 6;
  const int lane = tid & 63;
  const int l15  = lane & 15;
  const int quad = lane >> 4;
  const int wm   = (w >> 1) * 64;
  const int wn   = (w & 1) * 64;

  // Staging: wave-call r covers rows r*32 + w*8 + (lane>>3); lane covers 16B.
  // LDS dest LINEAR (gload_lds writes base+lane*16). Global source column is
  // PRE-SWIZZLED by the read-side involution: slot_g = (lane&7) ^ (row&7),
  // where row&7 == lane>>3 for all r,w. Read applies elem ^ ((row&7)<<3).
  const int srow  = w * 8 + (lane >> 3);
  const int sldsc = (lane & 7) * 8;                    // LDS col, linear
  const int sglbc = ((lane & 7) ^ (lane >> 3)) * 8;    // global col, pre-swz
  const unsigned short* aptr = Ag + (long)(m0 + srow) * lda + sglbc;
  const unsigned short* bptr = Bg + (long)(n0 + srow) * ldb + sglbc;

  f32x4 acc[4][4];
#pragma unroll
  for (int i = 0; i < 4; ++i)
#pragma unroll
    for (int j = 0; j < 4; ++j) acc[i][j] = (f32x4)(0.0f);

  const int nt = K >> 6;   // K/BK tiles, >= 2 for all our launches

  // ---- prologue: stage tiles 0 and 1 (8 loads each per wave) ----
#pragma unroll
  for (int tt = 0; tt < 2; ++tt) {
#pragma unroll
    for (int r = 0; r < 4; ++r) {
      gload_lds16(aptr + (long)(r * 32) * lda + tt * BK,
                  &As[tt][(srow + r * 32) * BK + sldsc]);
      gload_lds16(bptr + (long)(r * 32) * ldb + tt * BK,
                  &Bs[tt][(srow + r * 32) * BK + sldsc]);
    }
  }
  asm volatile("s_waitcnt vmcnt(8)" ::: "memory");  // tile 0 landed (oldest 8)
  asm volatile("s_barrier" ::: "memory");

  for (int t = 0; t < nt; ++t) {
    const int cur = t & 1;
    // ---- compute tile t from buf[cur], XOR-swizzled reads ----
#pragma unroll
    for (int ks = 0; ks < BK; ks += 32) {
      bf16x8 af[4], bfv[4];
#pragma unroll
      for (int i = 0; i < 4; ++i) {
        const int row = wm + i * 16 + l15;
        af[i] = *reinterpret_cast<const bf16x8*>(
            &As[cur][(row * BK + ks + quad * 8) ^ ((row & 7) << 3)]);
      }
#pragma unroll
      for (int j = 0; j < 4; ++j) {
        const int row = wn + j * 16 + l15;
        bfv[j] = *reinterpret_cast<const bf16x8*>(
            &Bs[cur][(row * BK + ks + quad * 8) ^ ((row & 7) << 3)]);
      }
      __builtin_amdgcn_s_setprio(1);
#pragma unroll
      for (int i = 0; i < 4; ++i)
#pragma unroll
        for (int j = 0; j < 4; ++j)
          acc[i][j] = __builtin_amdgcn_mfma_f32_16x16x32_bf16(
              af[i], bfv[j], acc[i][j], 0, 0, 0);
      __builtin_amdgcn_s_setprio(0);
    }
    // all waves done reading buf[cur] (ds_reads fully consumed above)
    asm volatile("s_barrier" ::: "memory");
    if (t + 2 < nt) {
      // stage tile t+2 into the buffer just freed; keep 16 loads in flight
      const long k0 = (long)(t + 2) * BK;
#pragma unroll
      for (int r = 0; r < 4; ++r) {
        gload_lds16(aptr + (long)(r * 32) * lda + k0,
                    &As[cur][(srow + r * 32) * BK + sldsc]);
        gload_lds16(bptr + (long)(r * 32) * ldb + k0,
                    &Bs[cur][(srow + r * 32) * BK + sldsc]);
      }
      asm volatile("s_waitcnt vmcnt(8)" ::: "memory");  // tile t+1 landed
    } else {
      asm volatile("s_waitcnt vmcnt(0)" ::: "memory");  // tail drain
    }
    asm volatile("s_barrier" ::: "memory");
  }

  // epilogue: D row = wm+i*16+quad*4+r, col = wn+j*16+l15
#pragma unroll
  for (int i = 0; i < 4; ++i) {
#pragma unroll
    for (int j = 0; j < 4; ++j) {
#pragma unroll
      for (int r = 0; r < 4; ++r) {
        const int row = m0 + wm + i * 16 + quad * 4 + r;
        const int col = n0 + wn + j * 16 + l15;
        const float val = acc[i][j][r];
        if constexpr (sizeof(OT) == 2) {
          reinterpret_cast<__hip_bfloat16*>(Cg)[(long)row * ldc + col] =
              __float2bfloat16(val);
        } else {
          reinterpret_cast<float*>(Cg)[(long)row * ldc + col] = val;
        }
      }
    }
  }
}

// ---------------- masked softmax over q; f32 in-place + bf16 copy ----------
__global__ __launch_bounds__(256) void softmax_kernel(
    float* __restrict__ attn, unsigned short* __restrict__ attnb,
    const int* __restrict__ vlens) {
  __shared__ float smax[4], ssum[4];
  const long base = (long)blockIdx.x * LQ;
  const int vl = vlens[blockIdx.x >> 9];
  const int t = threadIdx.x;
  float x[8];
  float mx = -3.0e38f;
#pragma unroll
  for (int u = 0; u < 8; ++u) {
    const int q = u * 256 + t;
    float v = attn[base + q];
    if (q >= vl) v = -1000000.0f;
    x[u] = v;
    mx = fmaxf(mx, v);
  }
#pragma unroll
  for (int off = 32; off > 0; off >>= 1) mx = fmaxf(mx, __shfl_down(mx, off));
  if ((t & 63) == 0) smax[t >> 6] = mx;
  __syncthreads();
  mx = fmaxf(fmaxf(smax[0], smax[1]), fmaxf(smax[2], smax[3]));
  float s = 0.f;
#pragma unroll
  for (int u = 0; u < 8; ++u) { x[u] = __expf(x[u] - mx); s += x[u]; }
#pragma unroll
  for (int off = 32; off > 0; off >>= 1) s += __shfl_down(s, off);
  if ((t & 63) == 0) ssum[t >> 6] = s;
  __syncthreads();
  s = ssum[0] + ssum[1] + ssum[2] + ssum[3];
  const float inv = 1.0f / s;
#pragma unroll
  for (int u = 0; u < 8; ++u) {
    const float v = x[u] * inv;
    attn[base + u * 256 + t] = v;
    attnb[base + u * 256 + t] = f2b(v);
  }
}

extern "C" void kernel_launch(void* const* d_in, const int* in_sizes, int n_in,
                              void* d_out, int out_size, void* d_ws, size_t ws_size,
                              hipStream_t stream) {
  const float* queries = (const float*)d_in[0];
  const float* keys    = (const float*)d_in[1];
  const float* values  = (const float*)d_in[2];
  const int*   vlens   = (const int*)d_in[3];
  const float* W_q     = (const float*)d_in[4];
  const float* W_k     = (const float*)d_in[5];
  const float* W_v     = (const float*)d_in[6];
  const float* W_o     = (const float*)d_in[7];

  float* out  = (float*)d_out;                       // [32][512][1024]
  float* attn = out + (size_t)NB * DVAL * DHID;      // [32][512][2048] f32

  // workspace layout (aliased by liveness; peak ~239 MB)
  char* ws = (char*)d_ws;
  unsigned short* qb    = (unsigned short*)(ws + 0);          // 134.2 MB; later vT
  unsigned short* vT    = qb;                                  // alias (qb dead after logits)
  // region R [134.2M, 201.3M): kb/Pb/Gt/wkb early, attnb late (all dead by softmax)
  unsigned short* kb    = (unsigned short*)(ws + 134217728UL); // 8.4 MB  [32][128][1024] bf16
  float*          Pb    = (float*)(ws + 142606336UL);          // 16.8 MB [32][128][1024] f32
  unsigned short* Gt    = (unsigned short*)(ws + 159383552UL); // 2.1 MB  [1024][1024] bf16
  unsigned short* wkb   = (unsigned short*)(ws + 161480704UL); // 2.1 MB
  unsigned short* attnb = (unsigned short*)(ws + 134217728UL); // 67 MB alias of R
  unsigned short* Nb    = (unsigned short*)(ws + 201326592UL); // 33.5 MB; later Tb
  unsigned short* Tb    = Nb;                                  // alias (Nb dead after logits)
  unsigned short* wqb   = (unsigned short*)(ws + 234881024UL); // 2.1 MB
  unsigned short* wvT   = (unsigned short*)(ws + 236978176UL); // 2.1 MB

  // --- pre-pass conversions ---
  cvt_bf16_kernel<<<dim3(32768), 256, 0, stream>>>(queries, qb, (long)NB * LQ * DIN);
  cvt_bf16_kernel<<<dim3(512),   256, 0, stream>>>(W_q, wqb, (long)DIN * DHID);
  cvt_bf16_kernel<<<dim3(512),   256, 0, stream>>>(W_k, wkb, (long)DIN * DHID);
  transpose_bf16_kernel<<<dim3(16, 16, 1), 256, 0, stream>>>(W_v, wvT, DIN, DHID, 0, 0);
  kb_kernel<<<dim3(NB * 128), 256, 0, stream>>>(keys, kb);

  // Gt = W_q @ W_k^T : M=1024,N=1024,K=1024 (once, shared over batches)
  gemm_bt_kernel<__hip_bfloat16><<<dim3(8, 8, 1), 256, 0, stream>>>(
      wqb, wkb, (__hip_bfloat16*)Gt, 1024, 1024, 1024, 1024, 0, 0, 0);

  // P[b] = kb[b] @ Gt^T : M=128,N=1024,K=1024 -> f32
  gemm_bt_kernel<float><<<dim3(8, 1, NB), 256, 0, stream>>>(
      kb, Gt, Pb, 1024, 1024, 1024, 1024,
      (long)128 * 1024, 0, (long)128 * 1024);

  // Nb[b,v,i] = bf16((1/32) sum_k W_o[k,v] P[b,k,i])
  nb_kernel<<<dim3(NB * (DVAL / VB)), 256, 0, stream>>>(Pb, W_o, Nb);

  // logits[b] = Nb[b] @ qb[b]^T : M=512,N=2048,K=1024 -> d_out attn region
  gemm_bt_kernel<float><<<dim3(16, 4, NB), 256, 0, stream>>>(
      Nb, qb, attn, 1024, 1024, 1024, 2048,
      (long)512 * 1024, (long)2048 * 1024, (long)512 * 2048);

  // vT[b] = bf16(values[b]^T) : [2048,1024] -> [1024,2048]  (qb now dead)
  transpose_bf16_kernel<<<dim3(16, 32, NB), 256, 0, stream>>>(
      values, vT, LQ, DIN, (long)LQ * DIN, (long)DIN * LQ);

  softmax_kernel<<<dim3(NB * DVAL), 256, 0, stream>>>(attn, attnb, vlens);

  // T[b] = attnb[b] @ values[b] : M=512,N=1024,K=2048
  gemm_bt_kernel<__hip_bfloat16><<<dim3(8, 4, NB), 256, 0, stream>>>(
      attnb, vT, (__hip_bfloat16*)Tb, 2048, 2048, 2048, 1024,
      (long)512 * 2048, (long)1024 * 2048, (long)512 * 1024);

  // out[b] = T[b] @ W_v : M=512,N=1024,K=1024
  gemm_bt_kernel<float><<<dim3(8, 4, NB), 256, 0, stream>>>(
      Tb, wvT, out, 1024, 1024, 1024, 1024,
      (long)512 * 1024, 0, (long)512 * 1024);
}